// Round 1
// baseline (923.484 us; speedup 1.0000x reference)
//
#include <hip/hip_runtime.h>

typedef __attribute__((ext_vector_type(8))) short short8;
typedef __attribute__((ext_vector_type(4))) float f32x4;
typedef unsigned short ushort_t;
typedef __attribute__((ext_vector_type(4))) unsigned short ushort4v;

#define N_NODES 262144
#define NITER 32
// packed weight offsets in ushort elements
#define OFF_U 0
#define OFF_V 16384
#define OFF_W1 32768
#define OFF_W2 65536
#define PACKED_TOTAL 114688

__device__ __forceinline__ ushort_t f2b(float f) {
  union { float f; unsigned int u; } v; v.f = f;
  unsigned int r = (v.u + 0x7FFFu + ((v.u >> 16) & 1u)) >> 16;
  return (ushort_t)r;
}
__device__ __forceinline__ float b2f(ushort_t u) {
  union { unsigned int u; float f; } v; v.u = ((unsigned int)u) << 16;
  return v.f;
}

// Pack U,V,W1,W2 (f32 row-major [out,in]) into bf16 B-fragment-major layout:
// B[k][n] = W[n*K + k]; packed flat index = (kb*NN + n)*8 + j with k = kb*8+j.
__global__ void pack_weights(const float* __restrict__ U, const float* __restrict__ V,
                             const float* __restrict__ W1, const float* __restrict__ W2,
                             ushort_t* __restrict__ ws) {
  int p = blockIdx.x * 256 + threadIdx.x;
  if (p >= PACKED_TOTAL) return;
  float val;
  if (p < 16384) {                       // U: K=128, NN=128
    int j = p & 7, n = (p >> 3) & 127, kb = p >> 10;
    val = U[n * 128 + kb * 8 + j];
  } else if (p < 32768) {                // V
    int q = p - 16384; int j = q & 7, n = (q >> 3) & 127, kb = q >> 10;
    val = V[n * 128 + kb * 8 + j];
  } else if (p < 65536) {                // W1: K=256, NN=128
    int q = p - 32768; int j = q & 7, n = (q >> 3) & 127, kb = q >> 10;
    val = W1[n * 256 + kb * 8 + j];
  } else {                               // W2: K=128, NN=384
    int q = p - 65536; int j = q & 7; int nk = q >> 3; int n = nk % 384; int kb = nk / 384;
    val = W2[n * 128 + kb * 8 + j];
  }
  ws[p] = f2b(val);
}

__global__ __launch_bounds__(512, 2) void update_main(
    const float* __restrict__ vec, const float* __restrict__ scal,
    const float* __restrict__ b1, const float* __restrict__ b2,
    const ushort_t* __restrict__ wpk, float* __restrict__ out)
{
  // LDS: 50688 + 26112 + 26112 + 49664 = 152576 B -> 1 block/CU
  __shared__ __align__(16) float    u_s[96 * 132];   // u, f32, padded stride
  __shared__ __align__(16) ushort_t v_s[96 * 136];   // v, bf16
  __shared__ __align__(16) ushort_t un_s[96 * 136];  // Avec | (m_s + h_s)
  __shared__ __align__(16) float    o2_s[32 * 388];  // a|b|c f32

  ushort_t* Avec = un_s;             // [96][136] bf16, rows = 3n+i, cols = c
  ushort_t* m_s  = un_s;             // [32][264] bf16 (scalar || vnorm)
  ushort_t* h_s  = un_s + 32 * 264;  // [32][136] bf16

  const int t   = threadIdx.x;
  const int w   = t >> 6;    // wave 0..7
  const int l   = t & 63;
  const int q   = l >> 4;    // quad 0..3
  const int c16 = l & 15;
  const int nq  = t >> 7;    // 0..3 (node sub-index for elementwise passes)
  const int cc  = t & 127;   // channel for elementwise passes

  // ---- persistent weight B-fragments (registers, loaded once per block) ----
  const short8* pU  = (const short8*)(wpk + OFF_U);
  const short8* pV  = (const short8*)(wpk + OFF_V);
  const short8* pW1 = (const short8*)(wpk + OFF_W1);
  const short8* pW2 = (const short8*)(wpk + OFF_W2);
  short8 bU[4], bV[4], bW1f[8], bW2f[3][4];
#pragma unroll
  for (int ks = 0; ks < 4; ks++) {
    bU[ks] = pU[(ks * 4 + q) * 128 + 16 * w + c16];
    bV[ks] = pV[(ks * 4 + q) * 128 + 16 * w + c16];
  }
#pragma unroll
  for (int ks = 0; ks < 8; ks++)
    bW1f[ks] = pW1[(ks * 4 + q) * 128 + 16 * w + c16];
#pragma unroll
  for (int tt = 0; tt < 3; tt++)
#pragma unroll
    for (int ks = 0; ks < 4; ks++)
      bW2f[tt][ks] = pW2[(ks * 4 + q) * 384 + 48 * w + 16 * tt + c16];

  const float b1v = b1[16 * w + c16];
  float b2v[3];
#pragma unroll
  for (int tt = 0; tt < 3; tt++) b2v[tt] = b2[48 * w + 16 * tt + c16];

  const size_t nodeBase = (size_t)blockIdx.x * (NITER * 32);
  float* __restrict__ dvp = out;                          // [N][128][3]
  float* __restrict__ dsp = out + (size_t)N_NODES * 384;  // [N][128]

  // ---- prologue: stage iter 0 inputs into registers ----
  float4 va[6]; float4 sa[2];
  {
    const float4* pv = (const float4*)(vec + nodeBase * 384);
#pragma unroll
    for (int f = 0; f < 6; f++) va[f] = pv[t + f * 512];
    const float4* ps = (const float4*)(scal + nodeBase * 128);
    sa[0] = ps[t]; sa[1] = ps[t + 512];
  }

  for (int it = 0; it < NITER; ++it) {
    // ---- top: staged vec regs -> Avec bf16 [3n+i][c] ----
#pragma unroll
    for (int f = 0; f < 6; f++) {
      int e0 = t * 4 + f * 2048;
      float vals[4] = {va[f].x, va[f].y, va[f].z, va[f].w};
#pragma unroll
      for (int k = 0; k < 4; k++) {
        int e = e0 + k;
        int n = e / 384;
        int r = e - n * 384;
        int c = r / 3;
        int i = r - c * 3;
        Avec[(3 * n + i) * 136 + c] = f2b(vals[k]);
      }
    }
    __syncthreads();  // B1: Avec ready; also protects u_s/v_s vs prev epilogue

    // prefetch next iter vec (overlaps all compute below)
    if (it + 1 < NITER) {
      const float4* pv = (const float4*)(vec + (nodeBase + (size_t)(it + 1) * 32) * 384);
#pragma unroll
      for (int f = 0; f < 6; f++) va[f] = pv[t + f * 512];
    }

    // ---- phase A: u = vec@U^T, v = vec@V^T (per-wave N-tile = w) ----
#pragma unroll
    for (int mt = 0; mt < 6; mt++) {
      short8 af[4];
      const int arow = mt * 16 + c16;
#pragma unroll
      for (int ks = 0; ks < 4; ks++)
        af[ks] = *(const short8*)&Avec[arow * 136 + ks * 32 + q * 8];
      f32x4 aU = {0.f, 0.f, 0.f, 0.f}, aV = {0.f, 0.f, 0.f, 0.f};
#pragma unroll
      for (int ks = 0; ks < 4; ks++) {
        aU = __builtin_amdgcn_mfma_f32_16x16x32_bf16(af[ks], bU[ks], aU, 0, 0, 0);
        aV = __builtin_amdgcn_mfma_f32_16x16x32_bf16(af[ks], bV[ks], aV, 0, 0, 0);
      }
      const int col = 16 * w + c16;
#pragma unroll
      for (int r = 0; r < 4; r++) {
        int orow = mt * 16 + q * 4 + r;
        u_s[orow * 132 + col] = aU[r];
        v_s[orow * 136 + col] = f2b(aV[r]);
      }
    }
    __syncthreads();  // B2: u_s/v_s ready, Avec dead

    // ---- m = [scalar || vnorm] ----
#pragma unroll
    for (int f = 0; f < 2; f++) {
      int s0 = t * 4 + f * 2048;
      int n = s0 >> 7, c = s0 & 127;
      ushort4v pk;
      pk.x = f2b(sa[f].x); pk.y = f2b(sa[f].y); pk.z = f2b(sa[f].z); pk.w = f2b(sa[f].w);
      *(ushort4v*)&m_s[n * 264 + c] = pk;
    }
#pragma unroll
    for (int p = 0; p < 8; p++) {
      int n = p * 4 + nq;
      float v0 = b2f(v_s[(3 * n + 0) * 136 + cc]);
      float v1 = b2f(v_s[(3 * n + 1) * 136 + cc]);
      float v2 = b2f(v_s[(3 * n + 2) * 136 + cc]);
      float vn = sqrtf(v0 * v0 + v1 * v1 + v2 * v2 + 1e-8f);
      m_s[n * 264 + 128 + cc] = f2b(vn);
    }
    // prefetch next iter scalar
    if (it + 1 < NITER) {
      const float4* ps = (const float4*)(scal + (nodeBase + (size_t)(it + 1) * 32) * 128);
      sa[0] = ps[t]; sa[1] = ps[t + 512];
    }
    __syncthreads();  // B3: m_s ready

    // ---- phase B: h = silu(m @ W1^T + b1) ----
#pragma unroll
    for (int mt = 0; mt < 2; mt++) {
      short8 af[8];
      const int arow = mt * 16 + c16;
#pragma unroll
      for (int ks = 0; ks < 8; ks++)
        af[ks] = *(const short8*)&m_s[arow * 264 + ks * 32 + q * 8];
      f32x4 acc = {0.f, 0.f, 0.f, 0.f};
#pragma unroll
      for (int ks = 0; ks < 8; ks++)
        acc = __builtin_amdgcn_mfma_f32_16x16x32_bf16(af[ks], bW1f[ks], acc, 0, 0, 0);
      const int col = 16 * w + c16;
#pragma unroll
      for (int r = 0; r < 4; r++) {
        int orow = mt * 16 + q * 4 + r;
        float x = acc[r] + b1v;
        float sg = 1.f / (1.f + __expf(-x));
        h_s[orow * 136 + col] = f2b(x * sg);
      }
    }
    __syncthreads();  // B4: h_s ready

    // ---- phase C: o2 = h @ W2^T + b2 (wave w -> N-tiles 3w..3w+2) ----
#pragma unroll
    for (int mt = 0; mt < 2; mt++) {
      short8 af[4];
      const int arow = mt * 16 + c16;
#pragma unroll
      for (int ks = 0; ks < 4; ks++)
        af[ks] = *(const short8*)&h_s[arow * 136 + ks * 32 + q * 8];
#pragma unroll
      for (int tt = 0; tt < 3; tt++) {
        f32x4 acc = {0.f, 0.f, 0.f, 0.f};
#pragma unroll
        for (int ks = 0; ks < 4; ks++)
          acc = __builtin_amdgcn_mfma_f32_16x16x32_bf16(af[ks], bW2f[tt][ks], acc, 0, 0, 0);
        const int col = 48 * w + 16 * tt + c16;
#pragma unroll
        for (int r = 0; r < 4; r++) {
          int orow = mt * 16 + q * 4 + r;
          o2_s[orow * 388 + col] = acc[r] + b2v[tt];
        }
      }
    }
    __syncthreads();  // B5: o2_s ready

    // ---- epilogue: delta_v = u*a ; delta_s = b + c*dot(u,v) ----
    const size_t n0 = nodeBase + (size_t)it * 32;
#pragma unroll
    for (int p = 0; p < 8; p++) {
      int n = p * 4 + nq;
      float u0 = u_s[(3 * n + 0) * 132 + cc];
      float u1 = u_s[(3 * n + 1) * 132 + cc];
      float u2 = u_s[(3 * n + 2) * 132 + cc];
      float v0 = b2f(v_s[(3 * n + 0) * 136 + cc]);
      float v1 = b2f(v_s[(3 * n + 1) * 136 + cc]);
      float v2 = b2f(v_s[(3 * n + 2) * 136 + cc]);
      float av = o2_s[n * 388 + cc];
      float bv = o2_s[n * 388 + 128 + cc];
      float cv = o2_s[n * 388 + 256 + cc];
      float dot = u0 * v0 + u1 * v1 + u2 * v2;
      size_t base = (n0 + (size_t)n) * 128 + cc;
      dvp[base * 3 + 0] = u0 * av;
      dvp[base * 3 + 1] = u1 * av;
      dvp[base * 3 + 2] = u2 * av;
      dsp[base] = bv + cv * dot;
    }
    // no barrier needed: next top writes Avec region only (disjoint from
    // epilogue reads); B1 protects u_s/v_s before phase A overwrites.
  }
}

extern "C" void kernel_launch(void* const* d_in, const int* in_sizes, int n_in,
                              void* d_out, int out_size, void* d_ws, size_t ws_size,
                              hipStream_t stream) {
  const float* vec  = (const float*)d_in[0];
  const float* scal = (const float*)d_in[1];
  const float* U_w  = (const float*)d_in[2];
  const float* V_w  = (const float*)d_in[3];
  const float* W1   = (const float*)d_in[4];
  const float* b1   = (const float*)d_in[5];
  const float* W2   = (const float*)d_in[6];
  const float* b2   = (const float*)d_in[7];
  ushort_t* wpk = (ushort_t*)d_ws;
  float* out = (float*)d_out;

  pack_weights<<<(PACKED_TOTAL + 255) / 256, 256, 0, stream>>>(U_w, V_w, W1, W2, wpk);
  update_main<<<256, 512, 0, stream>>>(vec, scal, b1, b2, wpk, out);
}